// Round 2
// baseline (253.105 us; speedup 1.0000x reference)
//
#include <hip/hip_runtime.h>
#include <cstdint>
#include <cstddef>

// Causal self-attention, B=4 L=2048 D=1024 H=16 HD=64.
// I/O dtype: float32; internal compute bf16 MFMA.
// Round-12: gemm_qkv ported to the 256^2 8-phase template (T2+T3+T4+T5):
// BM=BN=256 BK=64, 8 waves (2Mx4N), 128KB dynamic LDS double-buffer,
// XOR-swizzled rows (src-side pre-swizzle for global_load_lds), loads for
// tile t+1 issued in a burst at iter-t start (one vmcnt(0) per K-tile,
// never mid-phase), raw s_barrier + per-phase {4-12 ds_read | barrier |
// lgkmcnt(0) | setprio(1) 16xMFMA setprio(0) | barrier}. XCD-swizzled grid.
// flash v8 (32x32 MFMA, in-reg P) and 128^2 proj GEMM unchanged.

typedef __attribute__((ext_vector_type(8))) __bf16 bf16x8;
typedef __attribute__((ext_vector_type(4))) __bf16 bf16x4;
typedef __attribute__((ext_vector_type(4))) float f32x4;
typedef __attribute__((ext_vector_type(16))) float f32x16;

__device__ __forceinline__ f32x4 mfma_bf16(bf16x8 a, bf16x8 b, f32x4 c) {
  return __builtin_amdgcn_mfma_f32_16x16x32_bf16(a, b, c, 0, 0, 0);
}

__device__ __forceinline__ f32x16 mfma32(bf16x8 a, bf16x8 b, f32x16 c) {
  return __builtin_amdgcn_mfma_f32_32x32x16_bf16(a, b, c, 0, 0, 0);
}

__device__ __forceinline__ unsigned cvtpk(float a, float b) {
  unsigned r;
  asm("v_cvt_pk_bf16_f32 %0, %1, %2" : "=v"(r) : "v"(a), "v"(b));
  return r;
}

__device__ __forceinline__ void async_copy16(const void* gsrc, void* ldsdst) {
  __builtin_amdgcn_global_load_lds(
      (const __attribute__((address_space(1))) void*)gsrc,
      (__attribute__((address_space(3))) void*)ldsdst, 16, 0, 0);
}

// ---------------- f32 -> bf16 elementwise (4 elems/thread) ------------------
__global__ __launch_bounds__(256) void f32_to_bf16(
    const float* __restrict__ in, __bf16* __restrict__ out) {
  const size_t i = ((size_t)blockIdx.x * 256 + threadIdx.x) * 4;
  const float4 v = *(const float4*)&in[i];
  bf16x4 o = {(__bf16)v.x, (__bf16)v.y, (__bf16)v.z, (__bf16)v.w};
  *(bf16x4*)&out[i] = o;
}

// ------------- f32 transpose + convert: out[c][r] = (bf16)in[r][c] ----------
__global__ __launch_bounds__(256) void transpose_f32_bf16(
    const float* __restrict__ in, __bf16* __restrict__ out, int R, int C) {
  __shared__ float tile[32][33];
  const int c0 = blockIdx.x * 32;
  const int r0 = blockIdx.y * 32;
  const int tx = threadIdx.x & 31;
  const int ty = threadIdx.x >> 5;  // 0..7
#pragma unroll
  for (int i = 0; i < 32; i += 8)
    tile[ty + i][tx] = in[(size_t)(r0 + ty + i) * C + c0 + tx];
  __syncthreads();
#pragma unroll
  for (int i = 0; i < 32; i += 8)
    out[(size_t)(c0 + ty + i) * R + r0 + tx] = (__bf16)tile[tx][ty + i];
}

// ---------------- proj GEMM: 128x128 tile, BK=32, 4 waves, m97 staging ------
__global__ __launch_bounds__(256) void gemm_bt_f32out(
    const __bf16* __restrict__ A, const __bf16* __restrict__ BT,
    float* __restrict__ C, int M, int N, int K) {
  __shared__ __bf16 As[128 * 32];
  __shared__ __bf16 Bs[128 * 32];
  const int tid = threadIdx.x;
  const int wave = tid >> 6;
  const int lane = tid & 63;
  const int n16 = lane & 15;
  const int quad = lane >> 4;
  const int m0 = blockIdx.x * 128;
  const int n0 = blockIdx.y * 128;
  const int wr = wave >> 1;
  const int wc = wave & 1;

  const f32x4 zero = {0.f, 0.f, 0.f, 0.f};
  f32x4 acc[4][4];
#pragma unroll
  for (int i = 0; i < 4; ++i)
#pragma unroll
    for (int j = 0; j < 4; ++j) acc[i][j] = zero;

  const int KT = K >> 5;
  for (int kt = 0; kt < KT; ++kt) {
    const int k0 = kt << 5;
#pragma unroll
    for (int r = 0; r < 2; ++r) {
      const int li = (r << 8) + tid;
      const int row = li >> 2;
      const int kp8 = (li & 3) << 3;
      const int lbase = ((r << 8) + (wave << 6)) << 3;
      async_copy16(&A[(size_t)(m0 + row) * K + k0 + kp8], &As[lbase]);
      async_copy16(&BT[(size_t)(n0 + row) * K + k0 + kp8], &Bs[lbase]);
    }
    __syncthreads();
    bf16x8 af[4], bf[4];
#pragma unroll
    for (int t = 0; t < 4; ++t) {
      af[t] = *(const bf16x8*)&As[(wr * 64 + t * 16 + n16) * 32 + quad * 8];
      bf[t] = *(const bf16x8*)&Bs[(wc * 64 + t * 16 + n16) * 32 + quad * 8];
    }
#pragma unroll
    for (int mt = 0; mt < 4; ++mt)
#pragma unroll
      for (int nt = 0; nt < 4; ++nt)
        acc[mt][nt] = mfma_bf16(af[mt], bf[nt], acc[mt][nt]);
    __syncthreads();
  }
#pragma unroll
  for (int mt = 0; mt < 4; ++mt) {
#pragma unroll
    for (int r = 0; r < 4; ++r) {
      const int m = m0 + wr * 64 + mt * 16 + quad * 4 + r;
#pragma unroll
      for (int nt = 0; nt < 4; ++nt) {
        const int n = n0 + wc * 64 + nt * 16 + n16;
        C[(size_t)m * N + n] = acc[mt][nt][r];
      }
    }
  }
}

// ---------------- QKV GEMM: 256^2 tile, BK=64, 8 waves, 8-phase -------------
// M=8192 N=3072 K=1024. Grid 384 flat (XCD-swizzled). Wave (wr,wc) owns
// rows wr*128..+127, cols wc*64..+63 (one head column-block). LDS (elems):
// buf0 A=0, B=16384; buf1 A=32768, B=49152. Rows are 64 elems (128B), chunk
// c (16B) stored at phys = c ^ (row&7) via pre-swizzled global source.
__global__ __launch_bounds__(512, 2) void gemm_qkv(
    const __bf16* __restrict__ A, const __bf16* __restrict__ BT,
    __bf16* __restrict__ Q, __bf16* __restrict__ Kh, __bf16* __restrict__ VT) {
  extern __shared__ __bf16 smem[];
  const int K = 1024;
  // bijective XCD swizzle: 384 blocks, 48 per XCD
  const int wg = (blockIdx.x & 7) * 48 + (blockIdx.x >> 3);
  const int bm = wg / 12;
  const int bn = wg % 12;
  const int m0 = bm << 8;
  const int n0 = bn << 8;

  const int tid = threadIdx.x;
  const int wave = tid >> 6;
  const int lane = tid & 63;
  const int n16 = lane & 15;
  const int quad = lane >> 4;
  const int wr = wave >> 2;  // 0..1
  const int wc = wave & 3;   // 0..3

  // staging: thread covers, for load i (0..3): row = i*64 + wave*8 + lane>>3,
  // logical chunk (lane&7)^(row&7) lands at phys lane&7 (linear LDS dest).
  const int srow = wave * 8 + (lane >> 3);
  const int schunk = ((lane & 7) ^ ((lane >> 3) & 7)) << 3;
  const __bf16* aS = &A[(size_t)(m0 + srow) * K + schunk];
  const __bf16* bS = &BT[(size_t)(n0 + srow) * K + schunk];
  __bf16* dstW = smem + wave * 512;  // wave-uniform base; +i*4096; +16384 for B

  const f32x4 zero = {0.f, 0.f, 0.f, 0.f};
  f32x4 acc[8][4];
#pragma unroll
  for (int i = 0; i < 8; ++i)
#pragma unroll
    for (int j = 0; j < 4; ++j) acc[i][j] = zero;

  // prologue: stage tile 0 -> buf0
#pragma unroll
  for (int i = 0; i < 4; ++i) {
    async_copy16(aS + (size_t)i * 65536, dstW + i * 4096);
    async_copy16(bS + (size_t)i * 65536, dstW + 16384 + i * 4096);
  }

  for (int t = 0; t < 16; ++t) {
    const int base = (t & 1) << 15;
    asm volatile("s_waitcnt vmcnt(0)" ::: "memory");  // tile t DMA done (ours)
    __builtin_amdgcn_s_barrier();                     // ... and everyone's
    if (t + 1 < 16) {  // burst-issue tile t+1 -> other buffer
      const int nbase = ((t + 1) & 1) << 15;
      const __bf16* aT = aS + (t + 1) * 64;
      const __bf16* bT = bS + (t + 1) * 64;
#pragma unroll
      for (int i = 0; i < 4; ++i) {
        async_copy16(aT + (size_t)i * 65536, dstW + nbase + i * 4096);
        async_copy16(bT + (size_t)i * 65536, dstW + nbase + 16384 + i * 4096);
      }
    }
    const __bf16* As = smem + base;
    const __bf16* Bs = smem + base + 16384;
    bf16x8 bfr[4][2];  // whole-tile B frags (shared by all 4 phases)
#pragma unroll
    for (int g = 0; g < 4; ++g)
#pragma unroll
      for (int kk = 0; kk < 2; ++kk) {
        const int row = wc * 64 + g * 16 + n16;
        const int phys = ((kk * 4 + quad) ^ (n16 & 7)) << 3;
        bfr[g][kk] = *(const bf16x8*)&Bs[row * 64 + phys];
      }
#pragma unroll
    for (int q = 0; q < 4; ++q) {  // phase: C-quadrant q (m-frags 2q,2q+1)
      bf16x8 afr[2][2];
#pragma unroll
      for (int fi = 0; fi < 2; ++fi)
#pragma unroll
        for (int kk = 0; kk < 2; ++kk) {
          const int row = wr * 128 + (2 * q + fi) * 16 + n16;
          const int phys = ((kk * 4 + quad) ^ (n16 & 7)) << 3;
          afr[fi][kk] = *(const bf16x8*)&As[row * 64 + phys];
        }
      __builtin_amdgcn_s_barrier();
      asm volatile("s_waitcnt lgkmcnt(0)" ::: "memory");
      __builtin_amdgcn_sched_barrier(0);
      __builtin_amdgcn_s_setprio(1);
#pragma unroll
      for (int fi = 0; fi < 2; ++fi)
#pragma unroll
        for (int g = 0; g < 4; ++g)
#pragma unroll
          for (int kk = 0; kk < 2; ++kk)
            acc[2 * q + fi][g] =
                mfma_bf16(afr[fi][kk], bfr[g][kk], acc[2 * q + fi][g]);
      __builtin_amdgcn_s_setprio(0);
      __builtin_amdgcn_s_barrier();
    }
  }

  // ---- epilogue: wave tile 128 x 64, via 4KB/wave LDS transpose scratch ----
  // (buf0 A-region is dead: last read iter 14, last DMA completed iter 15.)
  __bf16* tw = smem + wave * 2048;
  const int b = m0 >> 11;  // block's 256 rows never straddle a batch
  const int l0w = (m0 & 2047) + wr * 128;
  const int n = n0 + wc * 64;  // 0..3071, 64-aligned -> one head

  if (n < 2048) {
    // Q or K: store rows l, cols hd (64 = full head). 4 passes of 32 rows.
    const float QSCALE = 0.125f * 1.44269504089f;  // 1/sqrt(64)*log2(e)
    const bool isQ = (n < 1024);
    const int h = (n & 1023) >> 6;
    __bf16* dst = isQ ? Q : Kh;
    const size_t bbase = ((size_t)(b * 16 + h) * 2048) * 64;
#pragma unroll
    for (int p = 0; p < 4; ++p) {
#pragma unroll
      for (int fi = 0; fi < 2; ++fi) {
        const int f = 2 * p + fi;
#pragma unroll
        for (int g = 0; g < 4; ++g)
#pragma unroll
          for (int r = 0; r < 4; ++r) {
            const int hd = g * 16 + n16;
            const int mm = fi * 16 + quad * 4 + r;
            const float v = isQ ? acc[f][g][r] * QSCALE : acc[f][g][r];
            tw[mm * 64 + (((hd >> 3) ^ (mm & 7)) << 3) + (hd & 7)] =
                (__bf16)v;
          }
      }
#pragma unroll
      for (int i = 0; i < 4; ++i) {
        const int c = lane + 64 * i;
        const int row = c >> 3;  // l' within pass 0..31
        const int hd0 = (c & 7) << 3;
        const int phys = (c & 7) ^ (row & 7);
        const bf16x8 v = *(const bf16x8*)&tw[row * 64 + phys * 8];
        *(bf16x8*)&dst[bbase + (size_t)(l0w + p * 32 + row) * 64 + hd0] = v;
      }
    }
  } else {
    // V: transpose to VT[d][l], b128 stores along l. 2 hd-halves x 2 l-halves.
    const int h = (n - 2048) >> 6;
    const size_t bhead = (size_t)(b * 16 + h);
#pragma unroll
    for (int ph = 0; ph < 2; ++ph)
#pragma unroll
      for (int lh = 0; lh < 2; ++lh) {
#pragma unroll
        for (int gi = 0; gi < 2; ++gi) {
          const int g = 2 * ph + gi;
#pragma unroll
          for (int fi = 0; fi < 4; ++fi) {
            const int f = 4 * lh + fi;
#pragma unroll
            for (int r = 0; r < 4; ++r) {
              const int hdp = gi * 16 + n16;        // 0..31
              const int mm = fi * 16 + quad * 4 + r;  // 0..63
              const int phys = (mm >> 3) ^ (hdp & 7);
              tw[hdp * 64 + phys * 8 + (mm & 7)] = (__bf16)acc[f][g][r];
            }
          }
        }
#pragma unroll
        for (int i = 0; i < 4; ++i) {
          const int c = lane + 64 * i;
          const int row = c >> 3;  // hd within pass 0..31
          const int phys = (c & 7) ^ (row & 7);
          const bf16x8 v = *(const bf16x8*)&tw[row * 64 + phys * 8];
          *(bf16x8*)&VT[(bhead * 64 + ph * 32 + row) * 2048 + l0w + lh * 64 +
                        (c & 7) * 8] = v;
        }
      }
  }
}

// ---------------- flash attention v8 -----------------------------------------
// grid (64 bh, 8 p); block p does q-tiles p and 15-p (128 rows each; wave w
// owns rows w*32..+31) -> uniform 34 k-steps of 64 cols, DMA double-buffer,
// one barrier/step. S^T = mfma_32x32x16(K-frag, Q-frag): lane holds one
// q-column (q = lane&31), 16 k-rows per 32-k chunk. P->PV A-frags built
// in-register: cvt_pk_bf16 pairs + v_permlane32_swap (no P LDS round-trip).
__global__ __launch_bounds__(256, 2) void flash_attn(
    const __bf16* __restrict__ Q, const __bf16* __restrict__ Kh,
    const __bf16* __restrict__ VT, __bf16* __restrict__ Y) {
  __shared__ __bf16 Ks[2][64 * 64];  // [k-col][d], 8-chunk rows, phys=c^(row&7)
  __shared__ __bf16 Vs[2][64 * 64];  // [d][k-col], same swizzle
  const int bh = blockIdx.x;  // 0..63
  const int p = blockIdx.y;   // 0..7
  const int tid = threadIdx.x;
  const int wave = tid >> 6;
  const int lane = tid & 63;
  const int lrow = lane & 31;
  const int hi = lane >> 5;
  const int lswz = lane & 7;
  const __bf16* Qb = Q + (size_t)bh * 2048 * 64;
  const __bf16* Kb = Kh + (size_t)bh * 2048 * 64;
  const __bf16* Vb = VT + (size_t)bh * 64 * 2048;
  const int b = bh >> 4;
  const int h = bh & 15;
  const f32x16 zero16 = {0.f, 0.f, 0.f, 0.f, 0.f, 0.f, 0.f, 0.f,
                         0.f, 0.f, 0.f, 0.f, 0.f, 0.f, 0.f, 0.f};

  const int srow = tid >> 3;                            // 0..31
  const int sswz = ((tid & 7) ^ (srow & 7)) << 3;       // elem offset in row
  const size_t kg0 = (size_t)srow * 64 + sswz;
  const size_t kg1 = (size_t)(srow + 32) * 64 + sswz;   // (row+32)&7 == row&7
  const size_t vg0 = (size_t)srow * 2048 + sswz;
  const size_t vg1 = (size_t)(srow + 32) * 2048 + sswz;
  const int ldst0 = wave * 512;                         // wave-uniform bases
  const int ldst1 = 2048 + wave * 512;

#pragma unroll
  for (int tt = 0; tt < 2; ++tt) {
    const int t = tt ? 15 - p : p;
    const int q0w = t * 128 + wave * 32;
    const int myq = q0w + lrow;

    bf16x8 qf[4];
#pragma unroll
    for (int i = 0; i < 4; ++i)
      qf[i] = *(const bf16x8*)&Qb[(size_t)myq * 64 + i * 16 + hi * 8];

    f32x16 o0 = zero16, o1 = zero16;
    float lsum = 0.f;
    const int nsteps = 2 * (t + 1);

    __syncthreads();  // prior tile's readers of Ks/Vs done
    // prologue DMA into buf0
    async_copy16(&Kb[kg0], &Ks[0][ldst0]);
    async_copy16(&Kb[kg1], &Ks[0][ldst1]);
    async_copy16(&Vb[vg0], &Vs[0][ldst0]);
    async_copy16(&Vb[vg1], &Vs[0][ldst1]);

    for (int kt = 0; kt < nsteps; ++kt) {
      const int buf = kt & 1;
      const int c0 = kt << 6;
      __syncthreads();  // drains DMA for buf; prior step's LDS reads done
      if (kt + 1 < nsteps) {
        const int nb = buf ^ 1;
        const int cn = c0 + 64;
        async_copy16(&Kb[kg0 + (size_t)cn * 64], &Ks[nb][ldst0]);
        async_copy16(&Kb[kg1 + (size_t)cn * 64], &Ks[nb][ldst1]);
        async_copy16(&Vb[vg0 + cn], &Vs[nb][ldst0]);
        async_copy16(&Vb[vg1 + cn], &Vs[nb][ldst1]);
      }
      if (c0 > q0w + 31) continue;  // fully masked for this wave

      const __bf16* ks = Ks[buf];
      const __bf16* vs = Vs[buf];

      // S^T chunks: sc[ch] covers k = c0+ch*32+[(r&3)+8*(r>>2)+4*hi], q=lrow
      f32x16 sc[2];
#pragma unroll
      for (int ch = 0; ch < 2; ++ch) {
        sc[ch] = zero16;
#pragma unroll
        for (int i = 0; i < 4; ++i) {
          const bf16x8 kf = *(const bf16x8*)&ks[(ch * 32 + lrow) * 64 +
                                                (((2 * i + hi) ^ lswz) << 3)];
          sc[ch] = mfma32(kf, qf[i], sc[ch]);
        }
      }
      // exp2 (log2e folded into Q); mask only on the 1 diagonal step/wave
      if (c0 + 63 > q0w) {
#pragma unroll
        for (int ch = 0; ch < 2; ++ch)
#pragma unroll
          for (int r = 0; r < 16; ++r) {
            const int k = c0 + ch * 32 + (r & 3) + 8 * (r >> 2) + 4 * hi;
            float e = __builtin_amdgcn_exp2f(sc[ch][r]);
            e = (k <= myq) ? e : 0.f;
            sc[ch][r] = e;
            lsum += e;
          }
      } else {
#pragma unroll
        for (int ch = 0; ch < 2; ++ch)
#pragma unroll
          for (int r = 0; r < 16; ++r) {
            const float e = __builtin_amdgcn_exp2f(sc[ch][r]);
            sc[ch][r] = e;
            lsum += e;
          }
      }
      // PV: per 16-k chunk build P A-frag in-register (T12), 2 d-tiles
#pragma unroll
      for (int ch = 0; ch < 2; ++ch) {
#pragma unroll
        for (int kc = 0; kc < 2; ++kc) {
          unsigned c01 = cvtpk(sc[ch][kc * 8 + 0], sc[ch][kc * 8 + 1]);
          unsigned c23 = cvtpk(sc[ch][kc * 8 + 2], sc[ch][kc * 8 + 3]);
          unsigned c45 = cvtpk(sc[ch][kc * 8 + 4], sc[ch][kc * 8 + 5]);
          unsigned c67 = cvtpk(sc[ch][kc * 8 + 6], sc[ch][kc * 8 + 7]);
          asm("v_permlane32_swap_b32 %0, %1" : "+v"(c01), "+v"(c45));
          asm("v_permlane32_swap_b32 %0, %1" : "+v"(c23), "+v"(c67));
          union {
            unsigned u[4];
            bf16x8 v;
          } pu;
          pu.u[0] = c01;  // P[q=lrow][k = hi*8 + 0,1]
          pu.u[1] = c23;
          pu.u[2] = c45;
          pu.u[3] = c67;
          const int kch = ch * 4 + kc * 2 + hi;
          {
            const bf16x8 vf0 = *(const bf16x8*)&vs[(0 * 32 + lrow) * 64 +
                                                   ((kch ^ lswz) << 3)];
            o0 = mfma32(pu.v, vf0, o0);
            const bf16x8 vf1 = *(const bf16x8*)&vs[(1 * 32 + lrow) * 64 +
                                                   ((kch ^ lswz) << 3)];
            o1 = mfma32(pu.v, vf1, o1);
          }
        }
      }
    }

    // epilogue: lane's lsum covers q=lrow (its 32 of 64 k); partner lane^32
    // has the rest. O C-layout: col=d=lrow, row=q=(r&3)+8*(r>>2)+4*hi.
    lsum += __shfl_xor(lsum, 32);
    const float inv = 1.0f / lsum;
    float invr[16];
#pragma unroll
    for (int r = 0; r < 16; ++r)
      invr[r] = __shfl(inv, (r & 3) + 8 * (r >> 2) + 4 * hi);
#pragma unroll
    for (int r = 0; r < 16; ++r) {
      const int row = q0w + (r & 3) + 8 * (r >> 2) + 4 * hi;
      const size_t yb = (size_t)(b * 2048 + row) * 1024 + h * 64;
      Y[yb + lrow] = (__bf16)(o0[r] * invr[r]);
      Y[yb + 32 + lrow] = (__bf16)(o1[r] * invr[r]);
    }
  }
}

// ---------------- launch ------------------------------------------------------
extern "C" void kernel_launch(void* const* d_in, const int* in_sizes, int n_in,
                              void* d_out, int out_size, void* d_ws,
                              size_t ws_size, hipStream_t stream) {
  const float* x = (const float*)d_in[0];      // [4,2048,1024] f32
  const float* Wqkv = (const float*)d_in[1];   // [1024,3072] f32
  const float* Wproj = (const float*)d_in[2];  // [1024,1024] f32
  float* out = (float*)d_out;                  // [4,2048,1024] f32

  char* ws = (char*)d_ws;  // ~75 MB
  __bf16* xb = (__bf16*)ws;     ws += (size_t)8192 * 1024 * 2;
  __bf16* WqkvT = (__bf16*)ws;  ws += (size_t)3072 * 1024 * 2;
  __bf16* WprojT = (__bf16*)ws; ws += (size_t)1024 * 1024 * 2;
  __bf16* Qs = (__bf16*)ws;     ws += (size_t)64 * 2048 * 64 * 2;
  __bf16* Ks = (__bf16*)ws;     ws += (size_t)64 * 2048 * 64 * 2;
  __bf16* VTs = (__bf16*)ws;    ws += (size_t)64 * 64 * 2048 * 2;
  __bf16* attn = xb;  // xb is dead after gemm_qkv; reuse its space

  static bool attrSet = false;
  if (!attrSet) {
    hipFuncSetAttribute((const void*)gemm_qkv,
                        hipFuncAttributeMaxDynamicSharedMemorySize, 131072);
    attrSet = true;
  }

  f32_to_bf16<<<8192, 256, 0, stream>>>(x, xb);
  transpose_f32_bf16<<<dim3(96, 32), 256, 0, stream>>>(Wqkv, WqkvT, 1024, 3072);
  transpose_f32_bf16<<<dim3(32, 32), 256, 0, stream>>>(Wproj, WprojT, 1024, 1024);
  gemm_qkv<<<384, 512, 131072, stream>>>(xb, WqkvT, Qs, Ks, VTs);
  flash_attn<<<dim3(64, 8), 256, 0, stream>>>(Qs, Ks, VTs, attn);
  gemm_bt_f32out<<<dim3(64, 8), 256, 0, stream>>>(attn, WprojT, out,
                                                  8192, 1024, 1024);
}

// Round 4
// 248.795 us; speedup vs baseline: 1.0173x; 1.0173x over previous
//
#include <hip/hip_runtime.h>
#include <cstdint>
#include <cstddef>

// Causal self-attention, B=4 L=2048 D=1024 H=16 HD=64.
// I/O dtype: float32; internal compute bf16 MFMA.
// Round-14: fix round-13's staging race. The counted vmcnt(6) now sits
// BEFORE the end-barrier of the preceding phase group (end of P3/P7 and
// prologue), so the barrier certifies the next tile resident for ALL waves
// before anyone ds_reads it. (Round-13 waited vmcnt(6) then read
// immediately: a wave could read rows another wave's DMA hadn't landed.)
// Queue ledger (per thread): prologue 14 -> drain-8 = tile0; P3-end
// drain-8 = odd tile; P7-end drain-8 = next even tile; remainder always 6.

typedef __attribute__((ext_vector_type(8))) __bf16 bf16x8;
typedef __attribute__((ext_vector_type(4))) __bf16 bf16x4;
typedef __attribute__((ext_vector_type(4))) float f32x4;
typedef __attribute__((ext_vector_type(16))) float f32x16;

__device__ __forceinline__ f32x4 mfma_bf16(bf16x8 a, bf16x8 b, f32x4 c) {
  return __builtin_amdgcn_mfma_f32_16x16x32_bf16(a, b, c, 0, 0, 0);
}

__device__ __forceinline__ f32x16 mfma32(bf16x8 a, bf16x8 b, f32x16 c) {
  return __builtin_amdgcn_mfma_f32_32x32x16_bf16(a, b, c, 0, 0, 0);
}

__device__ __forceinline__ unsigned cvtpk(float a, float b) {
  unsigned r;
  asm("v_cvt_pk_bf16_f32 %0, %1, %2" : "=v"(r) : "v"(a), "v"(b));
  return r;
}

__device__ __forceinline__ void async_copy16(const void* gsrc, void* ldsdst) {
  __builtin_amdgcn_global_load_lds(
      (const __attribute__((address_space(1))) void*)gsrc,
      (__attribute__((address_space(3))) void*)ldsdst, 16, 0, 0);
}

// ---------------- f32 -> bf16 elementwise (4 elems/thread) ------------------
__global__ __launch_bounds__(256) void f32_to_bf16(
    const float* __restrict__ in, __bf16* __restrict__ out) {
  const size_t i = ((size_t)blockIdx.x * 256 + threadIdx.x) * 4;
  const float4 v = *(const float4*)&in[i];
  bf16x4 o = {(__bf16)v.x, (__bf16)v.y, (__bf16)v.z, (__bf16)v.w};
  *(bf16x4*)&out[i] = o;
}

// ------------- f32 transpose + convert: out[c][r] = (bf16)in[r][c] ----------
__global__ __launch_bounds__(256) void transpose_f32_bf16(
    const float* __restrict__ in, __bf16* __restrict__ out, int R, int C) {
  __shared__ float tile[32][33];
  const int c0 = blockIdx.x * 32;
  const int r0 = blockIdx.y * 32;
  const int tx = threadIdx.x & 31;
  const int ty = threadIdx.x >> 5;  // 0..7
#pragma unroll
  for (int i = 0; i < 32; i += 8)
    tile[ty + i][tx] = in[(size_t)(r0 + ty + i) * C + c0 + tx];
  __syncthreads();
#pragma unroll
  for (int i = 0; i < 32; i += 8)
    out[(size_t)(c0 + ty + i) * R + r0 + tx] = (__bf16)tile[tx][ty + i];
}

// ---------------- proj GEMM: 128x128 tile, BK=32, 4 waves, m97 staging ------
__global__ __launch_bounds__(256) void gemm_bt_f32out(
    const __bf16* __restrict__ A, const __bf16* __restrict__ BT,
    float* __restrict__ C, int M, int N, int K) {
  __shared__ __bf16 As[128 * 32];
  __shared__ __bf16 Bs[128 * 32];
  const int tid = threadIdx.x;
  const int wave = tid >> 6;
  const int lane = tid & 63;
  const int n16 = lane & 15;
  const int quad = lane >> 4;
  const int m0 = blockIdx.x * 128;
  const int n0 = blockIdx.y * 128;
  const int wr = wave >> 1;
  const int wc = wave & 1;

  const f32x4 zero = {0.f, 0.f, 0.f, 0.f};
  f32x4 acc[4][4];
#pragma unroll
  for (int i = 0; i < 4; ++i)
#pragma unroll
    for (int j = 0; j < 4; ++j) acc[i][j] = zero;

  const int KT = K >> 5;
  for (int kt = 0; kt < KT; ++kt) {
    const int k0 = kt << 5;
#pragma unroll
    for (int r = 0; r < 2; ++r) {
      const int li = (r << 8) + tid;
      const int row = li >> 2;
      const int kp8 = (li & 3) << 3;
      const int lbase = ((r << 8) + (wave << 6)) << 3;
      async_copy16(&A[(size_t)(m0 + row) * K + k0 + kp8], &As[lbase]);
      async_copy16(&BT[(size_t)(n0 + row) * K + k0 + kp8], &Bs[lbase]);
    }
    __syncthreads();
    bf16x8 af[4], bf[4];
#pragma unroll
    for (int t = 0; t < 4; ++t) {
      af[t] = *(const bf16x8*)&As[(wr * 64 + t * 16 + n16) * 32 + quad * 8];
      bf[t] = *(const bf16x8*)&Bs[(wc * 64 + t * 16 + n16) * 32 + quad * 8];
    }
#pragma unroll
    for (int mt = 0; mt < 4; ++mt)
#pragma unroll
      for (int nt = 0; nt < 4; ++nt)
        acc[mt][nt] = mfma_bf16(af[mt], bf[nt], acc[mt][nt]);
    __syncthreads();
  }
#pragma unroll
  for (int mt = 0; mt < 4; ++mt) {
#pragma unroll
    for (int r = 0; r < 4; ++r) {
      const int m = m0 + wr * 64 + mt * 16 + quad * 4 + r;
#pragma unroll
      for (int nt = 0; nt < 4; ++nt) {
        const int n = n0 + wc * 64 + nt * 16 + n16;
        C[(size_t)m * N + n] = acc[mt][nt][r];
      }
    }
  }
}

// ---------------- QKV GEMM: 256^2 tile, BK=64, 8 waves, 8-phase -------------
// M=8192 N=3072 K=1024. Grid 384 flat (XCD-swizzled). Wave (wr,wc) owns
// rows wr*128..+127, cols wc*64..+63. LDS elems: buf0.A=0, buf0.B=16384,
// buf1.A=32768, buf1.B=49152 (buf0 = even K-tiles, buf1 = odd). Rows are
// 64 elems (128B); chunk c (16B) at phys c^(row&7) via pre-swizzled source.
// Stage unit = 64 rows = 1 load/thread = 4096 elems.
#define DS_B(Bs_)                                                            \
  _Pragma("unroll") for (int g = 0; g < 4; ++g)                              \
      _Pragma("unroll") for (int kk = 0; kk < 2; ++kk) bfr[g][kk] =          \
          *(const bf16x8*)&(Bs_)[(wc * 64 + g * 16 + n16) * 64 +             \
                                 (((kk * 4 + quad) ^ (n16 & 7)) << 3)];

#define DS_A2(As_, q_)                                                       \
  _Pragma("unroll") for (int fi = 0; fi < 2; ++fi)                           \
      _Pragma("unroll") for (int kk = 0; kk < 2; ++kk) af[fi][kk] =          \
          *(const bf16x8*)&(As_)[(wr * 128 + (2 * (q_) + fi) * 16 + n16) *   \
                                     64 +                                    \
                                 (((kk * 4 + quad) ^ (n16 & 7)) << 3)];

#define MFMA_BODY(q_)                                                        \
  __builtin_amdgcn_s_barrier();                                              \
  asm volatile("s_waitcnt lgkmcnt(0)" ::: "memory");                         \
  __builtin_amdgcn_sched_barrier(0);                                         \
  __builtin_amdgcn_s_setprio(1);                                             \
  _Pragma("unroll") for (int fi = 0; fi < 2; ++fi)                           \
      _Pragma("unroll") for (int g = 0; g < 4; ++g)                          \
          _Pragma("unroll") for (int kk = 0; kk < 2; ++kk)                   \
              acc[2 * (q_) + fi][g] =                                        \
      mfma_bf16(af[fi][kk], bfr[g][kk], acc[2 * (q_) + fi][g]);              \
  __builtin_amdgcn_s_setprio(0);

#define MFMA_PH(q_)                                                          \
  MFMA_BODY(q_)                                                              \
  __builtin_amdgcn_s_barrier();

// Phase group end: certify the NEXT tile resident (all waves) before the
// barrier, so the first reads of that tile (next phase) are race-free.
#define MFMA_PH_VM(q_)                                                       \
  MFMA_BODY(q_)                                                              \
  asm volatile("s_waitcnt vmcnt(6)" ::: "memory");                           \
  __builtin_amdgcn_s_barrier();

__global__ __launch_bounds__(512, 2) void gemm_qkv(
    const __bf16* __restrict__ A, const __bf16* __restrict__ BT,
    __bf16* __restrict__ Q, __bf16* __restrict__ Kh, __bf16* __restrict__ VT) {
  extern __shared__ __bf16 smem[];
  const int K = 1024;
  // bijective XCD swizzle: 384 blocks, 48 per XCD
  const int wg = (blockIdx.x & 7) * 48 + (blockIdx.x >> 3);
  const int bm = wg / 12;
  const int bn = wg % 12;
  const int m0 = bm << 8;
  const int n0 = bn << 8;

  const int tid = threadIdx.x;
  const int wave = tid >> 6;
  const int lane = tid & 63;
  const int n16 = lane & 15;
  const int quad = lane >> 4;
  const int wr = wave >> 2;  // 0..1
  const int wc = wave & 3;   // 0..3

  // staging: unit u = rows u*64..+63 of one K-tile. Thread covers
  // row = u*64 + (tid>>3), logical chunk (tid&7)^(row&7) -> linear LDS dest
  // unitbase + tid*8 elems (wave-uniform base + lane*16B).
  const int srow = tid >> 3;  // 0..63
  const int schunk = ((tid & 7) ^ (srow & 7)) << 3;
  const __bf16* aBase = &A[(size_t)(m0 + srow) * K + schunk];
  const __bf16* bBase = &BT[(size_t)(n0 + srow) * K + schunk];

  auto stgA = [&](int kt, int u, int half) {
    async_copy16(aBase + (size_t)u * 65536 + kt * 64,
                 smem + half * 32768 + u * 4096 + wave * 512);
  };
  auto stgB = [&](int kt, int u, int half) {
    async_copy16(bBase + (size_t)u * 65536 + kt * 64,
                 smem + half * 32768 + 16384 + u * 4096 + wave * 512);
  };

  const f32x4 zero = {0.f, 0.f, 0.f, 0.f};
  f32x4 acc[8][4];
#pragma unroll
  for (int i = 0; i < 8; ++i)
#pragma unroll
    for (int j = 0; j < 4; ++j) acc[i][j] = zero;

  const __bf16* As0 = smem;
  const __bf16* Bs0 = smem + 16384;
  const __bf16* As1 = smem + 32768;
  const __bf16* Bs1 = smem + 49152;

  // prologue: tiles 0 (buf0) and 1 (buf1) minus A-u13(1), in steady-state
  // queue order. Then certify tile 0 resident for everyone.
  stgB(0, 0, 0); stgB(0, 1, 0); stgB(0, 2, 0); stgB(0, 3, 0);
  stgA(0, 0, 0); stgA(0, 2, 0); stgA(0, 1, 0); stgA(0, 3, 0);
  stgB(1, 0, 1); stgB(1, 1, 1); stgB(1, 2, 1); stgB(1, 3, 1);
  stgA(1, 0, 1); stgA(1, 2, 1);
  asm volatile("s_waitcnt vmcnt(6)" ::: "memory");
  __builtin_amdgcn_s_barrier();

  for (int t = 0; t < 8; ++t) {
    const int knE = (2 * t + 2) & 15;  // next even tile (t=7: dummy wrap to 0)
    const int knO = (2 * t + 3) & 15;  // next odd tile  (t=7: dummy wrap to 1)
    bf16x8 bfr[4][2], af[2][2];

    // P0: q0 of even tile (resident since prev group-end barrier).
    // Stage A-u13(odd tile of THIS iter) -> buf1 (last read prev P7).
    DS_B(Bs0)
    DS_A2(As0, 0)
    stgA(2 * t + 1, 1, 1); stgA(2 * t + 1, 3, 1);
    asm volatile("s_waitcnt lgkmcnt(8)" ::: "memory");
    MFMA_PH(0)
    // P1: q1 even. Stage B-u01(next even) (buf0.B last read P0).
    DS_A2(As0, 1)
    stgB(knE, 0, 0); stgB(knE, 1, 0);
    MFMA_PH(1)
    // P2: q2 even. Stage B-u23(next even).
    DS_A2(As0, 2)
    stgB(knE, 2, 0); stgB(knE, 3, 0);
    MFMA_PH(2)
    // P3: q3 even. Stage A-u02(next even) (u0/u2 last read P1).
    // Group end: drain odd tile (8 oldest) before barrier.
    DS_A2(As0, 3)
    stgA(knE, 0, 0); stgA(knE, 2, 0);
    MFMA_PH_VM(3)
    // P4: q0 of odd tile. Stage A-u13(next even) (u1/u3 last read P3).
    DS_B(Bs1)
    DS_A2(As1, 0)
    stgA(knE, 1, 0); stgA(knE, 3, 0);
    asm volatile("s_waitcnt lgkmcnt(8)" ::: "memory");
    MFMA_PH(0)
    // P5: q1 odd. Stage B-u01(next odd) (buf1.B last read P4).
    DS_A2(As1, 1)
    stgB(knO, 0, 1); stgB(knO, 1, 1);
    MFMA_PH(1)
    // P6: q2 odd. Stage B-u23(next odd).
    DS_A2(As1, 2)
    stgB(knO, 2, 1); stgB(knO, 3, 1);
    MFMA_PH(2)
    // P7: q3 odd. Stage A-u02(next odd) (buf1 u0/u2 last read P5).
    // Group end: drain next-even tile before barrier.
    DS_A2(As1, 3)
    stgA(knO, 0, 1); stgA(knO, 2, 1);
    MFMA_PH_VM(3)
  }
  asm volatile("s_waitcnt vmcnt(0)" ::: "memory");  // drain tail DMAs
  __builtin_amdgcn_s_barrier();

  // ---- epilogue: wave tile 128 x 64, via 4KB/wave LDS transpose scratch ----
  __bf16* tw = smem + wave * 2048;
  const int b = m0 >> 11;  // block's 256 rows never straddle a batch
  const int l0w = (m0 & 2047) + wr * 128;
  const int n = n0 + wc * 64;  // 0..3071, 64-aligned -> one head

  if (n < 2048) {
    // Q or K: store rows l, cols hd (64 = full head). 4 passes of 32 rows.
    const float QSCALE = 0.125f * 1.44269504089f;  // 1/sqrt(64)*log2(e)
    const bool isQ = (n < 1024);
    const int h = (n & 1023) >> 6;
    __bf16* dst = isQ ? Q : Kh;
    const size_t bbase = ((size_t)(b * 16 + h) * 2048) * 64;
#pragma unroll
    for (int p = 0; p < 4; ++p) {
#pragma unroll
      for (int fi = 0; fi < 2; ++fi) {
        const int f = 2 * p + fi;
#pragma unroll
        for (int g = 0; g < 4; ++g)
#pragma unroll
          for (int r = 0; r < 4; ++r) {
            const int hd = g * 16 + n16;
            const int mm = fi * 16 + quad * 4 + r;
            const float v = isQ ? acc[f][g][r] * QSCALE : acc[f][g][r];
            tw[mm * 64 + (((hd >> 3) ^ (mm & 7)) << 3) + (hd & 7)] =
                (__bf16)v;
          }
      }
#pragma unroll
      for (int i = 0; i < 4; ++i) {
        const int c = lane + 64 * i;
        const int row = c >> 3;  // l' within pass 0..31
        const int hd0 = (c & 7) << 3;
        const int phys = (c & 7) ^ (row & 7);
        const bf16x8 v = *(const bf16x8*)&tw[row * 64 + phys * 8];
        *(bf16x8*)&dst[bbase + (size_t)(l0w + p * 32 + row) * 64 + hd0] = v;
      }
      __builtin_amdgcn_s_barrier();
    }
  } else {
    // V: transpose to VT[d][l], b128 stores along l. 2 hd-halves x 2 l-halves.
    const int h = (n - 2048) >> 6;
    const size_t bhead = (size_t)(b * 16 + h);
#pragma unroll
    for (int ph = 0; ph < 2; ++ph)
#pragma unroll
      for (int lh = 0; lh < 2; ++lh) {
#pragma unroll
        for (int gi = 0; gi < 2; ++gi) {
          const int g = 2 * ph + gi;
#pragma unroll
          for (int fi = 0; fi < 4; ++fi) {
            const int f = 4 * lh + fi;
#pragma unroll
            for (int r = 0; r < 4; ++r) {
              const int hdp = gi * 16 + n16;          // 0..31
              const int mm = fi * 16 + quad * 4 + r;  // 0..63
              const int phys = (mm >> 3) ^ (hdp & 7);
              tw[hdp * 64 + phys * 8 + (mm & 7)] = (__bf16)acc[f][g][r];
            }
          }
        }
#pragma unroll
        for (int i = 0; i < 4; ++i) {
          const int c = lane + 64 * i;
          const int row = c >> 3;  // hd within pass 0..31
          const int phys = (c & 7) ^ (row & 7);
          const bf16x8 v = *(const bf16x8*)&tw[row * 64 + phys * 8];
          *(bf16x8*)&VT[(bhead * 64 + ph * 32 + row) * 2048 + l0w + lh * 64 +
                        (c & 7) * 8] = v;
        }
        __builtin_amdgcn_s_barrier();
      }
  }
}

// ---------------- flash attention v8 -----------------------------------------
// grid (64 bh, 8 p); block p does q-tiles p and 15-p (128 rows each; wave w
// owns rows w*32..+31) -> uniform 34 k-steps of 64 cols, DMA double-buffer,
// one barrier/step. S^T = mfma_32x32x16(K-frag, Q-frag): lane holds one
// q-column (q = lane&31), 16 k-rows per 32-k chunk. P->PV A-frags built
// in-register: cvt_pk_bf16 pairs + v_permlane32_swap (no P LDS round-trip).
__global__ __launch_bounds__(256, 2) void flash_attn(
    const __bf16* __restrict__ Q, const __bf16* __restrict__ Kh,
    const __bf16* __restrict__ VT, __bf16* __restrict__ Y) {
  __shared__ __bf16 Ks[2][64 * 64];  // [k-col][d], 8-chunk rows, phys=c^(row&7)
  __shared__ __bf16 Vs[2][64 * 64];  // [d][k-col], same swizzle
  const int bh = blockIdx.x;  // 0..63
  const int p = blockIdx.y;   // 0..7
  const int tid = threadIdx.x;
  const int wave = tid >> 6;
  const int lane = tid & 63;
  const int lrow = lane & 31;
  const int hi = lane >> 5;
  const int lswz = lane & 7;
  const __bf16* Qb = Q + (size_t)bh * 2048 * 64;
  const __bf16* Kb = Kh + (size_t)bh * 2048 * 64;
  const __bf16* Vb = VT + (size_t)bh * 64 * 2048;
  const int b = bh >> 4;
  const int h = bh & 15;
  const f32x16 zero16 = {0.f, 0.f, 0.f, 0.f, 0.f, 0.f, 0.f, 0.f,
                         0.f, 0.f, 0.f, 0.f, 0.f, 0.f, 0.f, 0.f};

  const int srow = tid >> 3;                            // 0..31
  const int sswz = ((tid & 7) ^ (srow & 7)) << 3;       // elem offset in row
  const size_t kg0 = (size_t)srow * 64 + sswz;
  const size_t kg1 = (size_t)(srow + 32) * 64 + sswz;   // (row+32)&7 == row&7
  const size_t vg0 = (size_t)srow * 2048 + sswz;
  const size_t vg1 = (size_t)(srow + 32) * 2048 + sswz;
  const int ldst0 = wave * 512;                         // wave-uniform bases
  const int ldst1 = 2048 + wave * 512;

#pragma unroll
  for (int tt = 0; tt < 2; ++tt) {
    const int t = tt ? 15 - p : p;
    const int q0w = t * 128 + wave * 32;
    const int myq = q0w + lrow;

    bf16x8 qf[4];
#pragma unroll
    for (int i = 0; i < 4; ++i)
      qf[i] = *(const bf16x8*)&Qb[(size_t)myq * 64 + i * 16 + hi * 8];

    f32x16 o0 = zero16, o1 = zero16;
    float lsum = 0.f;
    const int nsteps = 2 * (t + 1);

    __syncthreads();  // prior tile's readers of Ks/Vs done
    // prologue DMA into buf0
    async_copy16(&Kb[kg0], &Ks[0][ldst0]);
    async_copy16(&Kb[kg1], &Ks[0][ldst1]);
    async_copy16(&Vb[vg0], &Vs[0][ldst0]);
    async_copy16(&Vb[vg1], &Vs[0][ldst1]);

    for (int kt = 0; kt < nsteps; ++kt) {
      const int buf = kt & 1;
      const int c0 = kt << 6;
      __syncthreads();  // drains DMA for buf; prior step's LDS reads done
      if (kt + 1 < nsteps) {
        const int nb = buf ^ 1;
        const int cn = c0 + 64;
        async_copy16(&Kb[kg0 + (size_t)cn * 64], &Ks[nb][ldst0]);
        async_copy16(&Kb[kg1 + (size_t)cn * 64], &Ks[nb][ldst1]);
        async_copy16(&Vb[vg0 + cn], &Vs[nb][ldst0]);
        async_copy16(&Vb[vg1 + cn], &Vs[nb][ldst1]);
      }
      if (c0 > q0w + 31) continue;  // fully masked for this wave

      const __bf16* ks = Ks[buf];
      const __bf16* vs = Vs[buf];

      // S^T chunks: sc[ch] covers k = c0+ch*32+[(r&3)+8*(r>>2)+4*hi], q=lrow
      f32x16 sc[2];
#pragma unroll
      for (int ch = 0; ch < 2; ++ch) {
        sc[ch] = zero16;
#pragma unroll
        for (int i = 0; i < 4; ++i) {
          const bf16x8 kf = *(const bf16x8*)&ks[(ch * 32 + lrow) * 64 +
                                                (((2 * i + hi) ^ lswz) << 3)];
          sc[ch] = mfma32(kf, qf[i], sc[ch]);
        }
      }
      // exp2 (log2e folded into Q); mask only on the 1 diagonal step/wave
      if (c0 + 63 > q0w) {
#pragma unroll
        for (int ch = 0; ch < 2; ++ch)
#pragma unroll
          for (int r = 0; r < 16; ++r) {
            const int k = c0 + ch * 32 + (r & 3) + 8 * (r >> 2) + 4 * hi;
            float e = __builtin_amdgcn_exp2f(sc[ch][r]);
            e = (k <= myq) ? e : 0.f;
            sc[ch][r] = e;
            lsum += e;
          }
      } else {
#pragma unroll
        for (int ch = 0; ch < 2; ++ch)
#pragma unroll
          for (int r = 0; r < 16; ++r) {
            const float e = __builtin_amdgcn_exp2f(sc[ch][r]);
            sc[ch][r] = e;
            lsum += e;
          }
      }
      // PV: per 16-k chunk build P A-frag in-register (T12), 2 d-tiles
#pragma unroll
      for (int ch = 0; ch < 2; ++ch) {
#pragma unroll
        for (int kc = 0; kc < 2; ++kc) {
          unsigned c01 = cvtpk(sc[ch][kc * 8 + 0], sc[ch][kc * 8 + 1]);
          unsigned c23 = cvtpk(sc[ch][kc * 8 + 2], sc[ch][kc * 8 + 3]);
          unsigned c45 = cvtpk(sc[ch][kc * 8 + 4], sc[ch][kc * 8 + 5]);
          unsigned c67 = cvtpk(sc[ch][kc * 8 + 6], sc[ch][kc * 8 + 7]);
          asm("v_permlane32_swap_b32 %0, %1" : "+v"(c01), "+v"(c45));
          asm("v_permlane32_swap_b32 %0, %1" : "+v"(c23), "+v"(c67));
          union {
            unsigned u[4];
            bf16x8 v;
          } pu;
          pu.u[0] = c01;  // P[q=lrow][k = hi*8 + 0,1]
          pu.u[1] = c23;
          pu.u[2] = c45;
          pu.u[3] = c67;
          const int kch = ch * 4 + kc * 2 + hi;
          {
            const bf16x8 vf0 = *(const bf16x8*)&vs[(0 * 32 + lrow) * 64 +
                                                   ((kch ^ lswz) << 3)];
            o0 = mfma32(pu.v, vf0, o0);
            const bf16x8 vf1 = *(const bf16x8*)&vs[(1 * 32 + lrow) * 64 +
                                                   ((kch ^ lswz) << 3)];
            o1 = mfma32(pu.v, vf1, o1);
          }
        }
      }
    }

    // epilogue: lane's lsum covers q=lrow (its 32 of 64 k); partner lane^32
    // has the rest. O C-layout: col=d=lrow, row=q=(r&3)+8*(r>>2)+4*hi.
    lsum += __shfl_xor(lsum, 32);
    const float inv = 1.0f / lsum;
    float invr[16];
#pragma unroll
    for (int r = 0; r < 16; ++r)
      invr[r] = __shfl(inv, (r & 3) + 8 * (r >> 2) + 4 * hi);
#pragma unroll
    for (int r = 0; r < 16; ++r) {
      const int row = q0w + (r & 3) + 8 * (r >> 2) + 4 * hi;
      const size_t yb = (size_t)(b * 2048 + row) * 1024 + h * 64;
      Y[yb + lrow] = (__bf16)(o0[r] * invr[r]);
      Y[yb + 32 + lrow] = (__bf16)(o1[r] * invr[r]);
    }
  }
}

// ---------------- launch ------------------------------------------------------
extern "C" void kernel_launch(void* const* d_in, const int* in_sizes, int n_in,
                              void* d_out, int out_size, void* d_ws,
                              size_t ws_size, hipStream_t stream) {
  const float* x = (const float*)d_in[0];      // [4,2048,1024] f32
  const float* Wqkv = (const float*)d_in[1];   // [1024,3072] f32
  const float* Wproj = (const float*)d_in[2];  // [1024,1024] f32
  float* out = (float*)d_out;                  // [4,2048,1024] f32

  char* ws = (char*)d_ws;  // ~75 MB
  __bf16* xb = (__bf16*)ws;     ws += (size_t)8192 * 1024 * 2;
  __bf16* WqkvT = (__bf16*)ws;  ws += (size_t)3072 * 1024 * 2;
  __bf16* WprojT = (__bf16*)ws; ws += (size_t)1024 * 1024 * 2;
  __bf16* Qs = (__bf16*)ws;     ws += (size_t)64 * 2048 * 64 * 2;
  __bf16* Ks = (__bf16*)ws;     ws += (size_t)64 * 2048 * 64 * 2;
  __bf16* VTs = (__bf16*)ws;    ws += (size_t)64 * 64 * 2048 * 2;
  __bf16* attn = xb;  // xb is dead after gemm_qkv; reuse its space

  static bool attrSet = false;
  if (!attrSet) {
    hipFuncSetAttribute((const void*)gemm_qkv,
                        hipFuncAttributeMaxDynamicSharedMemorySize, 131072);
    attrSet = true;
  }

  f32_to_bf16<<<8192, 256, 0, stream>>>(x, xb);
  transpose_f32_bf16<<<dim3(96, 32), 256, 0, stream>>>(Wqkv, WqkvT, 1024, 3072);
  transpose_f32_bf16<<<dim3(32, 32), 256, 0, stream>>>(Wproj, WprojT, 1024, 1024);
  gemm_qkv<<<384, 512, 131072, stream>>>(xb, WqkvT, Qs, Ks, VTs);
  flash_attn<<<dim3(64, 8), 256, 0, stream>>>(Qs, Ks, VTs, attn);
  gemm_bt_f32out<<<dim3(64, 8), 256, 0, stream>>>(attn, WprojT, out,
                                                  8192, 1024, 1024);
}

// Round 5
// 239.520 us; speedup vs baseline: 1.0567x; 1.0387x over previous
//
#include <hip/hip_runtime.h>
#include <cstdint>
#include <cstddef>

// Causal self-attention, B=4 L=2048 D=1024 H=16 HD=64.
// I/O dtype: float32; internal compute bf16 MFMA.
// Round-15: fix GEMM launch geometry (round-4's in-loop util was ~60% = fine;
// the loss was the 384-block 1.5x dispatch tail). Both GEMMs re-tiled to
// BM=128 BN=256 (64x64 wave tiles, 8 waves): gemm_qkv grid 768 = 3 exact
// rounds; gemm_bt grid 256 = 1 exact round. Schedule: one 32-MFMA phase per
// K-tile, 3-deep LDS buffers (3x48KB), tile t+2 staged during phase t,
// vmcnt(6) before the post-MFMA barrier certifies tile t+1 (round-4's proven
// placement). Epilogues reuse round-1's verified 64x64-wave-tile code.

typedef __attribute__((ext_vector_type(8))) __bf16 bf16x8;
typedef __attribute__((ext_vector_type(4))) __bf16 bf16x4;
typedef __attribute__((ext_vector_type(4))) float f32x4;
typedef __attribute__((ext_vector_type(16))) float f32x16;

__device__ __forceinline__ f32x4 mfma_bf16(bf16x8 a, bf16x8 b, f32x4 c) {
  return __builtin_amdgcn_mfma_f32_16x16x32_bf16(a, b, c, 0, 0, 0);
}

__device__ __forceinline__ f32x16 mfma32(bf16x8 a, bf16x8 b, f32x16 c) {
  return __builtin_amdgcn_mfma_f32_32x32x16_bf16(a, b, c, 0, 0, 0);
}

__device__ __forceinline__ unsigned cvtpk(float a, float b) {
  unsigned r;
  asm("v_cvt_pk_bf16_f32 %0, %1, %2" : "=v"(r) : "v"(a), "v"(b));
  return r;
}

__device__ __forceinline__ void async_copy16(const void* gsrc, void* ldsdst) {
  __builtin_amdgcn_global_load_lds(
      (const __attribute__((address_space(1))) void*)gsrc,
      (__attribute__((address_space(3))) void*)ldsdst, 16, 0, 0);
}

// ---------------- f32 -> bf16 elementwise (4 elems/thread) ------------------
__global__ __launch_bounds__(256) void f32_to_bf16(
    const float* __restrict__ in, __bf16* __restrict__ out) {
  const size_t i = ((size_t)blockIdx.x * 256 + threadIdx.x) * 4;
  const float4 v = *(const float4*)&in[i];
  bf16x4 o = {(__bf16)v.x, (__bf16)v.y, (__bf16)v.z, (__bf16)v.w};
  *(bf16x4*)&out[i] = o;
}

// ------------- f32 transpose + convert: out[c][r] = (bf16)in[r][c] ----------
__global__ __launch_bounds__(256) void transpose_f32_bf16(
    const float* __restrict__ in, __bf16* __restrict__ out, int R, int C) {
  __shared__ float tile[32][33];
  const int c0 = blockIdx.x * 32;
  const int r0 = blockIdx.y * 32;
  const int tx = threadIdx.x & 31;
  const int ty = threadIdx.x >> 5;  // 0..7
#pragma unroll
  for (int i = 0; i < 32; i += 8)
    tile[ty + i][tx] = in[(size_t)(r0 + ty + i) * C + c0 + tx];
  __syncthreads();
#pragma unroll
  for (int i = 0; i < 32; i += 8)
    out[(size_t)(c0 + ty + i) * R + r0 + tx] = (__bf16)tile[tx][ty + i];
}

// ======== shared 128x256 GEMM core, BK=64, 8 waves (2Mx4N), 3-deep =========
// 16 K-tiles. LDS buffer b (48KB = 24576 elems): A at b*24576 (8192 elems),
// B at b*24576+8192 (16384 elems). Rows = 64 elems (128B); 16B chunk c of
// row r stored at phys chunk c^(r&7) via pre-swizzled global source.
// Per phase t: {16 ds_read (tile t) | stage tile t+2 (6 loads) | barrier |
// lgkmcnt(0) | setprio(1) 32xMFMA setprio(0) | vmcnt(6) | barrier}.
// vmcnt(6) drains tile t+1's 6 loads (oldest pending), leaving t+2 in flight.

#define GEMM128x256_CORE(Aptr, Bptr)                                         \
  const int srow = tid >> 3; /* 0..63 */                                     \
  const int schunk = ((tid & 7) ^ (srow & 7)) << 3;                          \
  const __bf16* aBase = &(Aptr)[(size_t)(m0 + srow) * 1024 + schunk];        \
  const __bf16* bBase = &(Bptr)[(size_t)(n0 + srow) * 1024 + schunk];        \
  auto stgTile = [&](int kt, int b3) {                                       \
    __bf16* dst = smem + b3 * 24576 + wave * 512;                            \
    async_copy16(aBase + kt * 64, dst);                                      \
    async_copy16(aBase + 65536 + kt * 64, dst + 4096);                       \
    _Pragma("unroll") for (int u = 0; u < 4; ++u)                            \
        async_copy16(bBase + (size_t)u * 65536 + kt * 64,                    \
                     dst + 8192 + u * 4096);                                 \
  };                                                                         \
  const f32x4 zero = {0.f, 0.f, 0.f, 0.f};                                   \
  f32x4 acc[4][4];                                                           \
  _Pragma("unroll") for (int i = 0; i < 4; ++i)                              \
      _Pragma("unroll") for (int j = 0; j < 4; ++j) acc[i][j] = zero;        \
  stgTile(0, 0);                                                             \
  stgTile(1, 1);                                                             \
  asm volatile("s_waitcnt vmcnt(6)" ::: "memory"); /* tile 0 resident */     \
  __builtin_amdgcn_s_barrier();                                              \
  for (int t = 0; t < 16; ++t) {                                             \
    const __bf16* As = smem + (t % 3) * 24576;                               \
    const __bf16* Bs = As + 8192;                                            \
    bf16x8 af[4][2], bfr[4][2];                                              \
    _Pragma("unroll") for (int mt = 0; mt < 4; ++mt)                         \
        _Pragma("unroll") for (int kk = 0; kk < 2; ++kk) af[mt][kk] =        \
            *(const bf16x8*)&As[(wr * 64 + mt * 16 + n16) * 64 +             \
                                (((kk * 4 + quad) ^ (n16 & 7)) << 3)];       \
    _Pragma("unroll") for (int nt = 0; nt < 4; ++nt)                         \
        _Pragma("unroll") for (int kk = 0; kk < 2; ++kk) bfr[nt][kk] =       \
            *(const bf16x8*)&Bs[(wc * 64 + nt * 16 + n16) * 64 +             \
                                (((kk * 4 + quad) ^ (n16 & 7)) << 3)];       \
    stgTile((t + 2) & 15, (t + 2) % 3); /* dummy wrap at t=14,15 */          \
    __builtin_amdgcn_s_barrier();                                            \
    asm volatile("s_waitcnt lgkmcnt(0)" ::: "memory");                       \
    __builtin_amdgcn_sched_barrier(0);                                       \
    __builtin_amdgcn_s_setprio(1);                                           \
    _Pragma("unroll") for (int mt = 0; mt < 4; ++mt)                         \
        _Pragma("unroll") for (int nt = 0; nt < 4; ++nt)                     \
            _Pragma("unroll") for (int kk = 0; kk < 2; ++kk)                 \
                acc[mt][nt] = mfma_bf16(af[mt][kk], bfr[nt][kk],             \
                                        acc[mt][nt]);                        \
    __builtin_amdgcn_s_setprio(0);                                           \
    asm volatile("s_waitcnt vmcnt(6)" ::: "memory"); /* tile t+1 ready */    \
    __builtin_amdgcn_s_barrier();                                            \
  }                                                                          \
  asm volatile("s_waitcnt vmcnt(0)" ::: "memory"); /* drain dummies */       \
  __builtin_amdgcn_s_barrier();

// ---------------- QKV GEMM: M=8192 N=3072, grid 768 (3 exact rounds) --------
__global__ __launch_bounds__(512, 2) void gemm_qkv(
    const __bf16* __restrict__ A, const __bf16* __restrict__ BT,
    __bf16* __restrict__ Q, __bf16* __restrict__ Kh, __bf16* __restrict__ VT) {
  extern __shared__ __bf16 smem[];
  // bijective XCD swizzle: 768 blocks, 96 per XCD
  const int wg = (blockIdx.x & 7) * 96 + (blockIdx.x >> 3);
  const int bm = wg / 12;  // 0..63
  const int bn = wg % 12;  // 0..11
  const int m0 = bm << 7;
  const int n0 = bn << 8;
  const int tid = threadIdx.x;
  const int wave = tid >> 6;
  const int lane = tid & 63;
  const int n16 = lane & 15;
  const int quad = lane >> 4;
  const int wr = wave >> 2;  // 0..1
  const int wc = wave & 3;   // 0..3

  GEMM128x256_CORE(A, BT)

  // ---- epilogue: 64x64 wave tile via 4KB/wave LDS scratch (round-1 code) ---
  __bf16* tw = smem + wave * 2048;
  const int b = m0 >> 11;  // 128 | 2048: block never straddles a batch
  const int l0w = (m0 & 2047) + wr * 64;
  const int n = n0 + wc * 64;  // 64-aligned -> exactly one head

  if (n < 2048) {
    const float QSCALE = 0.125f * 1.44269504089f;  // 1/sqrt(64)*log2(e)
    const bool isQ = (n < 1024);
    const int h = (n & 1023) >> 6;
    __bf16* dst = isQ ? Q : Kh;
    const size_t base = ((size_t)(b * 16 + h) * 2048) * 64;
#pragma unroll
    for (int pass = 0; pass < 2; ++pass) {
#pragma unroll
      for (int mt = 2 * pass; mt < 2 * pass + 2; ++mt) {
#pragma unroll
        for (int nt = 0; nt < 4; ++nt)
#pragma unroll
          for (int r = 0; r < 4; ++r) {
            const int hd = nt * 16 + n16;
            const int mm = (mt & 1) * 16 + quad * 4 + r;
            const float v = isQ ? acc[mt][nt][r] * QSCALE : acc[mt][nt][r];
            tw[mm * 64 + (((hd >> 3) ^ (mm & 7)) << 3) + (hd & 7)] =
                (__bf16)v;
          }
      }
#pragma unroll
      for (int i = 0; i < 4; ++i) {
        const int c = lane + 64 * i;
        const int row = c >> 3;  // l' within pass, 0..31
        const int hd0 = (c & 7) << 3;
        const int phys = (c & 7) ^ (row & 7);
        const bf16x8 v = *(const bf16x8*)&tw[row * 64 + phys * 8];
        *(bf16x8*)&dst[base + (size_t)(l0w + pass * 32 + row) * 64 + hd0] = v;
      }
    }
  } else {
    // V: transpose to VT[d][l], b128 stores along l.
    const int h = (n - 2048) >> 6;
    const size_t bhead = (size_t)(b * 16 + h);
#pragma unroll
    for (int pass = 0; pass < 2; ++pass) {
#pragma unroll
      for (int nt = 2 * pass; nt < 2 * pass + 2; ++nt) {
#pragma unroll
        for (int mt = 0; mt < 4; ++mt)
#pragma unroll
          for (int r = 0; r < 4; ++r) {
            const int hdp = (nt & 1) * 16 + n16;
            const int mm = mt * 16 + quad * 4 + r;
            const int phys = (mm >> 3) ^ (hdp & 7);
            tw[hdp * 64 + phys * 8 + (mm & 7)] = (__bf16)acc[mt][nt][r];
          }
      }
#pragma unroll
      for (int i = 0; i < 4; ++i) {
        const int c = lane + 64 * i;
        const int row = c >> 3;
        const int phys = (c & 7) ^ (row & 7);
        const bf16x8 v = *(const bf16x8*)&tw[row * 64 + phys * 8];
        *(bf16x8*)&VT[(bhead * 64 + pass * 32 + row) * 2048 + l0w +
                      (c & 7) * 8] = v;
      }
    }
  }
}

// ---------------- proj GEMM: M=8192 N=1024, grid 256 (1 exact round) --------
__global__ __launch_bounds__(512, 2) void gemm_bt_f32out(
    const __bf16* __restrict__ A, const __bf16* __restrict__ BT,
    float* __restrict__ C) {
  extern __shared__ __bf16 smem[];
  // bijective XCD swizzle: 256 blocks, 32 per XCD
  const int wg = (blockIdx.x & 7) * 32 + (blockIdx.x >> 3);
  const int bm = wg >> 2;  // 0..63
  const int bn = wg & 3;   // 0..3
  const int m0 = bm << 7;
  const int n0 = bn << 8;
  const int tid = threadIdx.x;
  const int wave = tid >> 6;
  const int lane = tid & 63;
  const int n16 = lane & 15;
  const int quad = lane >> 4;
  const int wr = wave >> 2;  // 0..1
  const int wc = wave & 3;   // 0..3

  GEMM128x256_CORE(A, BT)

  // direct f32 stores: 16-lane-contiguous n -> 64B segments
#pragma unroll
  for (int mt = 0; mt < 4; ++mt) {
#pragma unroll
    for (int r = 0; r < 4; ++r) {
      const int m = m0 + wr * 64 + mt * 16 + quad * 4 + r;
#pragma unroll
      for (int nt = 0; nt < 4; ++nt) {
        const int nn = n0 + wc * 64 + nt * 16 + n16;
        C[(size_t)m * 1024 + nn] = acc[mt][nt][r];
      }
    }
  }
}

// ---------------- flash attention v8 -----------------------------------------
// grid (64 bh, 8 p); block p does q-tiles p and 15-p (128 rows each; wave w
// owns rows w*32..+31) -> uniform 34 k-steps of 64 cols, DMA double-buffer,
// one barrier/step. S^T = mfma_32x32x16(K-frag, Q-frag): lane holds one
// q-column (q = lane&31), 16 k-rows per 32-k chunk. P->PV A-frags built
// in-register: cvt_pk_bf16 pairs + v_permlane32_swap (no P LDS round-trip).
__global__ __launch_bounds__(256, 2) void flash_attn(
    const __bf16* __restrict__ Q, const __bf16* __restrict__ Kh,
    const __bf16* __restrict__ VT, __bf16* __restrict__ Y) {
  __shared__ __bf16 Ks[2][64 * 64];  // [k-col][d], 8-chunk rows, phys=c^(row&7)
  __shared__ __bf16 Vs[2][64 * 64];  // [d][k-col], same swizzle
  const int bh = blockIdx.x;  // 0..63
  const int p = blockIdx.y;   // 0..7
  const int tid = threadIdx.x;
  const int wave = tid >> 6;
  const int lane = tid & 63;
  const int lrow = lane & 31;
  const int hi = lane >> 5;
  const int lswz = lane & 7;
  const __bf16* Qb = Q + (size_t)bh * 2048 * 64;
  const __bf16* Kb = Kh + (size_t)bh * 2048 * 64;
  const __bf16* Vb = VT + (size_t)bh * 64 * 2048;
  const int b = bh >> 4;
  const int h = bh & 15;
  const f32x16 zero16 = {0.f, 0.f, 0.f, 0.f, 0.f, 0.f, 0.f, 0.f,
                         0.f, 0.f, 0.f, 0.f, 0.f, 0.f, 0.f, 0.f};

  const int srow = tid >> 3;                            // 0..31
  const int sswz = ((tid & 7) ^ (srow & 7)) << 3;       // elem offset in row
  const size_t kg0 = (size_t)srow * 64 + sswz;
  const size_t kg1 = (size_t)(srow + 32) * 64 + sswz;   // (row+32)&7 == row&7
  const size_t vg0 = (size_t)srow * 2048 + sswz;
  const size_t vg1 = (size_t)(srow + 32) * 2048 + sswz;
  const int ldst0 = wave * 512;                         // wave-uniform bases
  const int ldst1 = 2048 + wave * 512;

#pragma unroll
  for (int tt = 0; tt < 2; ++tt) {
    const int t = tt ? 15 - p : p;
    const int q0w = t * 128 + wave * 32;
    const int myq = q0w + lrow;

    bf16x8 qf[4];
#pragma unroll
    for (int i = 0; i < 4; ++i)
      qf[i] = *(const bf16x8*)&Qb[(size_t)myq * 64 + i * 16 + hi * 8];

    f32x16 o0 = zero16, o1 = zero16;
    float lsum = 0.f;
    const int nsteps = 2 * (t + 1);

    __syncthreads();  // prior tile's readers of Ks/Vs done
    // prologue DMA into buf0
    async_copy16(&Kb[kg0], &Ks[0][ldst0]);
    async_copy16(&Kb[kg1], &Ks[0][ldst1]);
    async_copy16(&Vb[vg0], &Vs[0][ldst0]);
    async_copy16(&Vb[vg1], &Vs[0][ldst1]);

    for (int kt = 0; kt < nsteps; ++kt) {
      const int buf = kt & 1;
      const int c0 = kt << 6;
      __syncthreads();  // drains DMA for buf; prior step's LDS reads done
      if (kt + 1 < nsteps) {
        const int nb = buf ^ 1;
        const int cn = c0 + 64;
        async_copy16(&Kb[kg0 + (size_t)cn * 64], &Ks[nb][ldst0]);
        async_copy16(&Kb[kg1 + (size_t)cn * 64], &Ks[nb][ldst1]);
        async_copy16(&Vb[vg0 + cn], &Vs[nb][ldst0]);
        async_copy16(&Vb[vg1 + cn], &Vs[nb][ldst1]);
      }
      if (c0 > q0w + 31) continue;  // fully masked for this wave

      const __bf16* ks = Ks[buf];
      const __bf16* vs = Vs[buf];

      // S^T chunks: sc[ch] covers k = c0+ch*32+[(r&3)+8*(r>>2)+4*hi], q=lrow
      f32x16 sc[2];
#pragma unroll
      for (int ch = 0; ch < 2; ++ch) {
        sc[ch] = zero16;
#pragma unroll
        for (int i = 0; i < 4; ++i) {
          const bf16x8 kf = *(const bf16x8*)&ks[(ch * 32 + lrow) * 64 +
                                                (((2 * i + hi) ^ lswz) << 3)];
          sc[ch] = mfma32(kf, qf[i], sc[ch]);
        }
      }
      // exp2 (log2e folded into Q); mask only on the 1 diagonal step/wave
      if (c0 + 63 > q0w) {
#pragma unroll
        for (int ch = 0; ch < 2; ++ch)
#pragma unroll
          for (int r = 0; r < 16; ++r) {
            const int k = c0 + ch * 32 + (r & 3) + 8 * (r >> 2) + 4 * hi;
            float e = __builtin_amdgcn_exp2f(sc[ch][r]);
            e = (k <= myq) ? e : 0.f;
            sc[ch][r] = e;
            lsum += e;
          }
      } else {
#pragma unroll
        for (int ch = 0; ch < 2; ++ch)
#pragma unroll
          for (int r = 0; r < 16; ++r) {
            const float e = __builtin_amdgcn_exp2f(sc[ch][r]);
            sc[ch][r] = e;
            lsum += e;
          }
      }
      // PV: per 16-k chunk build P A-frag in-register (T12), 2 d-tiles
#pragma unroll
      for (int ch = 0; ch < 2; ++ch) {
#pragma unroll
        for (int kc = 0; kc < 2; ++kc) {
          unsigned c01 = cvtpk(sc[ch][kc * 8 + 0], sc[ch][kc * 8 + 1]);
          unsigned c23 = cvtpk(sc[ch][kc * 8 + 2], sc[ch][kc * 8 + 3]);
          unsigned c45 = cvtpk(sc[ch][kc * 8 + 4], sc[ch][kc * 8 + 5]);
          unsigned c67 = cvtpk(sc[ch][kc * 8 + 6], sc[ch][kc * 8 + 7]);
          asm("v_permlane32_swap_b32 %0, %1" : "+v"(c01), "+v"(c45));
          asm("v_permlane32_swap_b32 %0, %1" : "+v"(c23), "+v"(c67));
          union {
            unsigned u[4];
            bf16x8 v;
          } pu;
          pu.u[0] = c01;  // P[q=lrow][k = hi*8 + 0,1]
          pu.u[1] = c23;
          pu.u[2] = c45;
          pu.u[3] = c67;
          const int kch = ch * 4 + kc * 2 + hi;
          {
            const bf16x8 vf0 = *(const bf16x8*)&vs[(0 * 32 + lrow) * 64 +
                                                   ((kch ^ lswz) << 3)];
            o0 = mfma32(pu.v, vf0, o0);
            const bf16x8 vf1 = *(const bf16x8*)&vs[(1 * 32 + lrow) * 64 +
                                                   ((kch ^ lswz) << 3)];
            o1 = mfma32(pu.v, vf1, o1);
          }
        }
      }
    }

    // epilogue: lane's lsum covers q=lrow (its 32 of 64 k); partner lane^32
    // has the rest. O C-layout: col=d=lrow, row=q=(r&3)+8*(r>>2)+4*hi.
    lsum += __shfl_xor(lsum, 32);
    const float inv = 1.0f / lsum;
    float invr[16];
#pragma unroll
    for (int r = 0; r < 16; ++r)
      invr[r] = __shfl(inv, (r & 3) + 8 * (r >> 2) + 4 * hi);
#pragma unroll
    for (int r = 0; r < 16; ++r) {
      const int row = q0w + (r & 3) + 8 * (r >> 2) + 4 * hi;
      const size_t yb = (size_t)(b * 2048 + row) * 1024 + h * 64;
      Y[yb + lrow] = (__bf16)(o0[r] * invr[r]);
      Y[yb + 32 + lrow] = (__bf16)(o1[r] * invr[r]);
    }
  }
}

// ---------------- launch ------------------------------------------------------
extern "C" void kernel_launch(void* const* d_in, const int* in_sizes, int n_in,
                              void* d_out, int out_size, void* d_ws,
                              size_t ws_size, hipStream_t stream) {
  const float* x = (const float*)d_in[0];      // [4,2048,1024] f32
  const float* Wqkv = (const float*)d_in[1];   // [1024,3072] f32
  const float* Wproj = (const float*)d_in[2];  // [1024,1024] f32
  float* out = (float*)d_out;                  // [4,2048,1024] f32

  char* ws = (char*)d_ws;  // ~75 MB
  __bf16* xb = (__bf16*)ws;     ws += (size_t)8192 * 1024 * 2;
  __bf16* WqkvT = (__bf16*)ws;  ws += (size_t)3072 * 1024 * 2;
  __bf16* WprojT = (__bf16*)ws; ws += (size_t)1024 * 1024 * 2;
  __bf16* Qs = (__bf16*)ws;     ws += (size_t)64 * 2048 * 64 * 2;
  __bf16* Ks = (__bf16*)ws;     ws += (size_t)64 * 2048 * 64 * 2;
  __bf16* VTs = (__bf16*)ws;    ws += (size_t)64 * 64 * 2048 * 2;
  __bf16* attn = xb;  // xb is dead after gemm_qkv; reuse its space

  static bool attrSet = false;
  if (!attrSet) {
    hipFuncSetAttribute((const void*)gemm_qkv,
                        hipFuncAttributeMaxDynamicSharedMemorySize, 147456);
    hipFuncSetAttribute((const void*)gemm_bt_f32out,
                        hipFuncAttributeMaxDynamicSharedMemorySize, 147456);
    attrSet = true;
  }

  f32_to_bf16<<<8192, 256, 0, stream>>>(x, xb);
  transpose_f32_bf16<<<dim3(96, 32), 256, 0, stream>>>(Wqkv, WqkvT, 1024, 3072);
  transpose_f32_bf16<<<dim3(32, 32), 256, 0, stream>>>(Wproj, WprojT, 1024, 1024);
  gemm_qkv<<<768, 512, 147456, stream>>>(xb, WqkvT, Qs, Ks, VTs);
  flash_attn<<<dim3(64, 8), 256, 0, stream>>>(Qs, Ks, VTs, attn);
  gemm_bt_f32out<<<256, 512, 147456, stream>>>(attn, WprojT, out);
}

// Round 6
// 227.690 us; speedup vs baseline: 1.1116x; 1.0520x over previous
//
#include <hip/hip_runtime.h>
#include <cstdint>
#include <cstddef>

// Causal self-attention, B=4 L=2048 D=1024 H=16 HD=64.
// I/O dtype: float32; internal compute bf16 MFMA.
// Round-16: cross-block TLP for the GEMMs. All schedule variants at 1
// block/CU plateaued at MfmaUtil ~31% (50% of cycles idle at barriers —
// 8 lockstep waves, nothing else resident). Switch to 128^2 tiles, 4 waves,
// BK=64, 2-deep 64KB LDS -> 2 blocks/CU: one block's MFMA covers the other
// block's vmcnt/barrier stalls (m114 mechanism). Exact rounds preserved:
// qkv grid 1536 = 3x512, proj 512 = 1x512, XCD-swizzled. Wave tile 64x64
// -> round-1's verified transpose epilogues verbatim.

typedef __attribute__((ext_vector_type(8))) __bf16 bf16x8;
typedef __attribute__((ext_vector_type(4))) __bf16 bf16x4;
typedef __attribute__((ext_vector_type(4))) float f32x4;
typedef __attribute__((ext_vector_type(16))) float f32x16;

__device__ __forceinline__ f32x4 mfma_bf16(bf16x8 a, bf16x8 b, f32x4 c) {
  return __builtin_amdgcn_mfma_f32_16x16x32_bf16(a, b, c, 0, 0, 0);
}

__device__ __forceinline__ f32x16 mfma32(bf16x8 a, bf16x8 b, f32x16 c) {
  return __builtin_amdgcn_mfma_f32_32x32x16_bf16(a, b, c, 0, 0, 0);
}

__device__ __forceinline__ unsigned cvtpk(float a, float b) {
  unsigned r;
  asm("v_cvt_pk_bf16_f32 %0, %1, %2" : "=v"(r) : "v"(a), "v"(b));
  return r;
}

__device__ __forceinline__ void async_copy16(const void* gsrc, void* ldsdst) {
  __builtin_amdgcn_global_load_lds(
      (const __attribute__((address_space(1))) void*)gsrc,
      (__attribute__((address_space(3))) void*)ldsdst, 16, 0, 0);
}

// ---------------- f32 -> bf16 elementwise (4 elems/thread) ------------------
__global__ __launch_bounds__(256) void f32_to_bf16(
    const float* __restrict__ in, __bf16* __restrict__ out) {
  const size_t i = ((size_t)blockIdx.x * 256 + threadIdx.x) * 4;
  const float4 v = *(const float4*)&in[i];
  bf16x4 o = {(__bf16)v.x, (__bf16)v.y, (__bf16)v.z, (__bf16)v.w};
  *(bf16x4*)&out[i] = o;
}

// ------------- f32 transpose + convert: out[c][r] = (bf16)in[r][c] ----------
__global__ __launch_bounds__(256) void transpose_f32_bf16(
    const float* __restrict__ in, __bf16* __restrict__ out, int R, int C) {
  __shared__ float tile[32][33];
  const int c0 = blockIdx.x * 32;
  const int r0 = blockIdx.y * 32;
  const int tx = threadIdx.x & 31;
  const int ty = threadIdx.x >> 5;  // 0..7
#pragma unroll
  for (int i = 0; i < 32; i += 8)
    tile[ty + i][tx] = in[(size_t)(r0 + ty + i) * C + c0 + tx];
  __syncthreads();
#pragma unroll
  for (int i = 0; i < 32; i += 8)
    out[(size_t)(c0 + ty + i) * R + r0 + tx] = (__bf16)tile[tx][ty + i];
}

// ======== shared 128x128 GEMM core, BK=64, 4 waves (2Mx2N), 2-deep ==========
// 16 K-tiles of K=1024. LDS buffer b (32KB = 16384 elems): A at b*16384
// (8192 elems = 128 rows x 64), B at +8192. Rows 64 elems (128B); 16B chunk
// c of row r at phys c^(r&7) via pre-swizzled global source. Staging: 8
// loads/thread/K-tile (4 A-units + 4 B-units of 32 rows). Per iter t:
// {16 ds_read(t) | stage t+1 -> buf^1 | barrier | lgkm(0) | setprio(1)
// 32xMFMA setprio(0) | vmcnt(0) (t+1 resident; stall hidden by co-resident
// block) | barrier}.
#define GEMM128x128_CORE(Aptr, Bptr)                                         \
  const int srow32 = tid >> 3; /* 0..31 */                                   \
  const int schunk = ((tid & 7) ^ (srow32 & 7)) << 3;                        \
  const __bf16* aBase = &(Aptr)[(size_t)(m0 + srow32) * 1024 + schunk];      \
  const __bf16* bBase = &(Bptr)[(size_t)(n0 + srow32) * 1024 + schunk];      \
  auto stgTile = [&](int kt, int b2) {                                       \
    __bf16* dst = smem + b2 * 16384 + wave * 512;                            \
    _Pragma("unroll") for (int u = 0; u < 4; ++u)                            \
        async_copy16(aBase + (size_t)u * 32768 + kt * 64, dst + u * 2048);   \
    _Pragma("unroll") for (int u = 0; u < 4; ++u)                            \
        async_copy16(bBase + (size_t)u * 32768 + kt * 64,                    \
                     dst + 8192 + u * 2048);                                 \
  };                                                                         \
  const f32x4 zero = {0.f, 0.f, 0.f, 0.f};                                   \
  f32x4 acc[4][4];                                                           \
  _Pragma("unroll") for (int i = 0; i < 4; ++i)                              \
      _Pragma("unroll") for (int j = 0; j < 4; ++j) acc[i][j] = zero;        \
  stgTile(0, 0);                                                             \
  asm volatile("s_waitcnt vmcnt(0)" ::: "memory");                           \
  __builtin_amdgcn_s_barrier();                                              \
  for (int t = 0; t < 16; ++t) {                                             \
    const __bf16* As = smem + (t & 1) * 16384;                               \
    const __bf16* Bs = As + 8192;                                            \
    bf16x8 af[4][2], bfr[4][2];                                              \
    _Pragma("unroll") for (int mt = 0; mt < 4; ++mt)                         \
        _Pragma("unroll") for (int kk = 0; kk < 2; ++kk) af[mt][kk] =        \
            *(const bf16x8*)&As[(wr * 64 + mt * 16 + n16) * 64 +             \
                                (((kk * 4 + quad) ^ (n16 & 7)) << 3)];       \
    _Pragma("unroll") for (int nt = 0; nt < 4; ++nt)                         \
        _Pragma("unroll") for (int kk = 0; kk < 2; ++kk) bfr[nt][kk] =       \
            *(const bf16x8*)&Bs[(wc * 64 + nt * 16 + n16) * 64 +             \
                                (((kk * 4 + quad) ^ (n16 & 7)) << 3)];       \
    if (t < 15) stgTile(t + 1, (t + 1) & 1);                                 \
    __builtin_amdgcn_s_barrier();                                            \
    asm volatile("s_waitcnt lgkmcnt(0)" ::: "memory");                       \
    __builtin_amdgcn_sched_barrier(0);                                       \
    __builtin_amdgcn_s_setprio(1);                                           \
    _Pragma("unroll") for (int mt = 0; mt < 4; ++mt)                         \
        _Pragma("unroll") for (int nt = 0; nt < 4; ++nt)                     \
            _Pragma("unroll") for (int kk = 0; kk < 2; ++kk)                 \
                acc[mt][nt] = mfma_bf16(af[mt][kk], bfr[nt][kk],             \
                                        acc[mt][nt]);                        \
    __builtin_amdgcn_s_setprio(0);                                           \
    asm volatile("s_waitcnt vmcnt(0)" ::: "memory");                         \
    __builtin_amdgcn_s_barrier();                                            \
  }

// ---------------- QKV GEMM: M=8192 N=3072, grid 1536 (3 exact rounds) -------
__global__ __launch_bounds__(256, 2) void gemm_qkv(
    const __bf16* __restrict__ A, const __bf16* __restrict__ BT,
    __bf16* __restrict__ Q, __bf16* __restrict__ Kh, __bf16* __restrict__ VT) {
  extern __shared__ __bf16 smem[];
  // bijective XCD swizzle: 1536 blocks, 192 per XCD
  const int wg = (blockIdx.x & 7) * 192 + (blockIdx.x >> 3);
  const int bm = wg / 24;  // 0..63
  const int bn = wg % 24;  // 0..23
  const int m0 = bm << 7;
  const int n0 = bn << 7;
  const int tid = threadIdx.x;
  const int wave = tid >> 6;
  const int lane = tid & 63;
  const int n16 = lane & 15;
  const int quad = lane >> 4;
  const int wr = wave >> 1;  // 0..1
  const int wc = wave & 1;   // 0..1

  GEMM128x128_CORE(A, BT)

  // ---- epilogue: 64x64 wave tile via 4KB/wave LDS scratch (round-1 code) ---
  // (all DMA drained and all waves past final barrier -> smem reusable)
  __bf16* tw = smem + wave * 2048;
  const int b = m0 >> 11;  // 128 | 2048: block never straddles a batch
  const int l0w = (m0 & 2047) + wr * 64;
  const int n = n0 + wc * 64;  // 64-aligned -> exactly one head

  if (n < 2048) {
    const float QSCALE = 0.125f * 1.44269504089f;  // 1/sqrt(64)*log2(e)
    const bool isQ = (n < 1024);
    const int h = (n & 1023) >> 6;
    __bf16* dst = isQ ? Q : Kh;
    const size_t base = ((size_t)(b * 16 + h) * 2048) * 64;
#pragma unroll
    for (int pass = 0; pass < 2; ++pass) {
#pragma unroll
      for (int mt = 2 * pass; mt < 2 * pass + 2; ++mt) {
#pragma unroll
        for (int nt = 0; nt < 4; ++nt)
#pragma unroll
          for (int r = 0; r < 4; ++r) {
            const int hd = nt * 16 + n16;
            const int mm = (mt & 1) * 16 + quad * 4 + r;
            const float v = isQ ? acc[mt][nt][r] * QSCALE : acc[mt][nt][r];
            tw[mm * 64 + (((hd >> 3) ^ (mm & 7)) << 3) + (hd & 7)] =
                (__bf16)v;
          }
      }
#pragma unroll
      for (int i = 0; i < 4; ++i) {
        const int c = lane + 64 * i;
        const int row = c >> 3;  // l' within pass, 0..31
        const int hd0 = (c & 7) << 3;
        const int phys = (c & 7) ^ (row & 7);
        const bf16x8 v = *(const bf16x8*)&tw[row * 64 + phys * 8];
        *(bf16x8*)&dst[base + (size_t)(l0w + pass * 32 + row) * 64 + hd0] = v;
      }
    }
  } else {
    // V: transpose to VT[d][l], b128 stores along l.
    const int h = (n - 2048) >> 6;
    const size_t bhead = (size_t)(b * 16 + h);
#pragma unroll
    for (int pass = 0; pass < 2; ++pass) {
#pragma unroll
      for (int nt = 2 * pass; nt < 2 * pass + 2; ++nt) {
#pragma unroll
        for (int mt = 0; mt < 4; ++mt)
#pragma unroll
          for (int r = 0; r < 4; ++r) {
            const int hdp = (nt & 1) * 16 + n16;
            const int mm = mt * 16 + quad * 4 + r;
            const int phys = (mm >> 3) ^ (hdp & 7);
            tw[hdp * 64 + phys * 8 + (mm & 7)] = (__bf16)acc[mt][nt][r];
          }
      }
#pragma unroll
      for (int i = 0; i < 4; ++i) {
        const int c = lane + 64 * i;
        const int row = c >> 3;
        const int phys = (c & 7) ^ (row & 7);
        const bf16x8 v = *(const bf16x8*)&tw[row * 64 + phys * 8];
        *(bf16x8*)&VT[(bhead * 64 + pass * 32 + row) * 2048 + l0w +
                      (c & 7) * 8] = v;
      }
    }
  }
}

// ---------------- proj GEMM: M=8192 N=1024, grid 512 (1 exact round) --------
__global__ __launch_bounds__(256, 2) void gemm_bt_f32out(
    const __bf16* __restrict__ A, const __bf16* __restrict__ BT,
    float* __restrict__ C) {
  extern __shared__ __bf16 smem[];
  // bijective XCD swizzle: 512 blocks, 64 per XCD
  const int wg = (blockIdx.x & 7) * 64 + (blockIdx.x >> 3);
  const int bm = wg >> 3;  // 0..63
  const int bn = wg & 7;   // 0..7
  const int m0 = bm << 7;
  const int n0 = bn << 7;
  const int tid = threadIdx.x;
  const int wave = tid >> 6;
  const int lane = tid & 63;
  const int n16 = lane & 15;
  const int quad = lane >> 4;
  const int wr = wave >> 1;  // 0..1
  const int wc = wave & 1;   // 0..1

  GEMM128x128_CORE(A, BT)

  // direct f32 stores: 16-lane-contiguous n -> 64B segments
#pragma unroll
  for (int mt = 0; mt < 4; ++mt) {
#pragma unroll
    for (int r = 0; r < 4; ++r) {
      const int m = m0 + wr * 64 + mt * 16 + quad * 4 + r;
#pragma unroll
      for (int nt = 0; nt < 4; ++nt) {
        const int nn = n0 + wc * 64 + nt * 16 + n16;
        C[(size_t)m * 1024 + nn] = acc[mt][nt][r];
      }
    }
  }
}

// ---------------- flash attention v8 -----------------------------------------
// grid (64 bh, 8 p); block p does q-tiles p and 15-p (128 rows each; wave w
// owns rows w*32..+31) -> uniform 34 k-steps of 64 cols, DMA double-buffer,
// one barrier/step. S^T = mfma_32x32x16(K-frag, Q-frag): lane holds one
// q-column (q = lane&31), 16 k-rows per 32-k chunk. P->PV A-frags built
// in-register: cvt_pk_bf16 pairs + v_permlane32_swap (no P LDS round-trip).
__global__ __launch_bounds__(256, 2) void flash_attn(
    const __bf16* __restrict__ Q, const __bf16* __restrict__ Kh,
    const __bf16* __restrict__ VT, __bf16* __restrict__ Y) {
  __shared__ __bf16 Ks[2][64 * 64];  // [k-col][d], 8-chunk rows, phys=c^(row&7)
  __shared__ __bf16 Vs[2][64 * 64];  // [d][k-col], same swizzle
  const int bh = blockIdx.x;  // 0..63
  const int p = blockIdx.y;   // 0..7
  const int tid = threadIdx.x;
  const int wave = tid >> 6;
  const int lane = tid & 63;
  const int lrow = lane & 31;
  const int hi = lane >> 5;
  const int lswz = lane & 7;
  const __bf16* Qb = Q + (size_t)bh * 2048 * 64;
  const __bf16* Kb = Kh + (size_t)bh * 2048 * 64;
  const __bf16* Vb = VT + (size_t)bh * 64 * 2048;
  const int b = bh >> 4;
  const int h = bh & 15;
  const f32x16 zero16 = {0.f, 0.f, 0.f, 0.f, 0.f, 0.f, 0.f, 0.f,
                         0.f, 0.f, 0.f, 0.f, 0.f, 0.f, 0.f, 0.f};

  const int srow = tid >> 3;                            // 0..31
  const int sswz = ((tid & 7) ^ (srow & 7)) << 3;       // elem offset in row
  const size_t kg0 = (size_t)srow * 64 + sswz;
  const size_t kg1 = (size_t)(srow + 32) * 64 + sswz;   // (row+32)&7 == row&7
  const size_t vg0 = (size_t)srow * 2048 + sswz;
  const size_t vg1 = (size_t)(srow + 32) * 2048 + sswz;
  const int ldst0 = wave * 512;                         // wave-uniform bases
  const int ldst1 = 2048 + wave * 512;

#pragma unroll
  for (int tt = 0; tt < 2; ++tt) {
    const int t = tt ? 15 - p : p;
    const int q0w = t * 128 + wave * 32;
    const int myq = q0w + lrow;

    bf16x8 qf[4];
#pragma unroll
    for (int i = 0; i < 4; ++i)
      qf[i] = *(const bf16x8*)&Qb[(size_t)myq * 64 + i * 16 + hi * 8];

    f32x16 o0 = zero16, o1 = zero16;
    float lsum = 0.f;
    const int nsteps = 2 * (t + 1);

    __syncthreads();  // prior tile's readers of Ks/Vs done
    // prologue DMA into buf0
    async_copy16(&Kb[kg0], &Ks[0][ldst0]);
    async_copy16(&Kb[kg1], &Ks[0][ldst1]);
    async_copy16(&Vb[vg0], &Vs[0][ldst0]);
    async_copy16(&Vb[vg1], &Vs[0][ldst1]);

    for (int kt = 0; kt < nsteps; ++kt) {
      const int buf = kt & 1;
      const int c0 = kt << 6;
      __syncthreads();  // drains DMA for buf; prior step's LDS reads done
      if (kt + 1 < nsteps) {
        const int nb = buf ^ 1;
        const int cn = c0 + 64;
        async_copy16(&Kb[kg0 + (size_t)cn * 64], &Ks[nb][ldst0]);
        async_copy16(&Kb[kg1 + (size_t)cn * 64], &Ks[nb][ldst1]);
        async_copy16(&Vb[vg0 + cn], &Vs[nb][ldst0]);
        async_copy16(&Vb[vg1 + cn], &Vs[nb][ldst1]);
      }
      if (c0 > q0w + 31) continue;  // fully masked for this wave

      const __bf16* ks = Ks[buf];
      const __bf16* vs = Vs[buf];

      // S^T chunks: sc[ch] covers k = c0+ch*32+[(r&3)+8*(r>>2)+4*hi], q=lrow
      f32x16 sc[2];
#pragma unroll
      for (int ch = 0; ch < 2; ++ch) {
        sc[ch] = zero16;
#pragma unroll
        for (int i = 0; i < 4; ++i) {
          const bf16x8 kf = *(const bf16x8*)&ks[(ch * 32 + lrow) * 64 +
                                                (((2 * i + hi) ^ lswz) << 3)];
          sc[ch] = mfma32(kf, qf[i], sc[ch]);
        }
      }
      // exp2 (log2e folded into Q); mask only on the 1 diagonal step/wave
      if (c0 + 63 > q0w) {
#pragma unroll
        for (int ch = 0; ch < 2; ++ch)
#pragma unroll
          for (int r = 0; r < 16; ++r) {
            const int k = c0 + ch * 32 + (r & 3) + 8 * (r >> 2) + 4 * hi;
            float e = __builtin_amdgcn_exp2f(sc[ch][r]);
            e = (k <= myq) ? e : 0.f;
            sc[ch][r] = e;
            lsum += e;
          }
      } else {
#pragma unroll
        for (int ch = 0; ch < 2; ++ch)
#pragma unroll
          for (int r = 0; r < 16; ++r) {
            const float e = __builtin_amdgcn_exp2f(sc[ch][r]);
            sc[ch][r] = e;
            lsum += e;
          }
      }
      // PV: per 16-k chunk build P A-frag in-register (T12), 2 d-tiles
#pragma unroll
      for (int ch = 0; ch < 2; ++ch) {
#pragma unroll
        for (int kc = 0; kc < 2; ++kc) {
          unsigned c01 = cvtpk(sc[ch][kc * 8 + 0], sc[ch][kc * 8 + 1]);
          unsigned c23 = cvtpk(sc[ch][kc * 8 + 2], sc[ch][kc * 8 + 3]);
          unsigned c45 = cvtpk(sc[ch][kc * 8 + 4], sc[ch][kc * 8 + 5]);
          unsigned c67 = cvtpk(sc[ch][kc * 8 + 6], sc[ch][kc * 8 + 7]);
          asm("v_permlane32_swap_b32 %0, %1" : "+v"(c01), "+v"(c45));
          asm("v_permlane32_swap_b32 %0, %1" : "+v"(c23), "+v"(c67));
          union {
            unsigned u[4];
            bf16x8 v;
          } pu;
          pu.u[0] = c01;  // P[q=lrow][k = hi*8 + 0,1]
          pu.u[1] = c23;
          pu.u[2] = c45;
          pu.u[3] = c67;
          const int kch = ch * 4 + kc * 2 + hi;
          {
            const bf16x8 vf0 = *(const bf16x8*)&vs[(0 * 32 + lrow) * 64 +
                                                   ((kch ^ lswz) << 3)];
            o0 = mfma32(pu.v, vf0, o0);
            const bf16x8 vf1 = *(const bf16x8*)&vs[(1 * 32 + lrow) * 64 +
                                                   ((kch ^ lswz) << 3)];
            o1 = mfma32(pu.v, vf1, o1);
          }
        }
      }
    }

    // epilogue: lane's lsum covers q=lrow (its 32 of 64 k); partner lane^32
    // has the rest. O C-layout: col=d=lrow, row=q=(r&3)+8*(r>>2)+4*hi.
    lsum += __shfl_xor(lsum, 32);
    const float inv = 1.0f / lsum;
    float invr[16];
#pragma unroll
    for (int r = 0; r < 16; ++r)
      invr[r] = __shfl(inv, (r & 3) + 8 * (r >> 2) + 4 * hi);
#pragma unroll
    for (int r = 0; r < 16; ++r) {
      const int row = q0w + (r & 3) + 8 * (r >> 2) + 4 * hi;
      const size_t yb = (size_t)(b * 2048 + row) * 1024 + h * 64;
      Y[yb + lrow] = (__bf16)(o0[r] * invr[r]);
      Y[yb + 32 + lrow] = (__bf16)(o1[r] * invr[r]);
    }
  }
}

// ---------------- launch ------------------------------------------------------
extern "C" void kernel_launch(void* const* d_in, const int* in_sizes, int n_in,
                              void* d_out, int out_size, void* d_ws,
                              size_t ws_size, hipStream_t stream) {
  const float* x = (const float*)d_in[0];      // [4,2048,1024] f32
  const float* Wqkv = (const float*)d_in[1];   // [1024,3072] f32
  const float* Wproj = (const float*)d_in[2];  // [1024,1024] f32
  float* out = (float*)d_out;                  // [4,2048,1024] f32

  char* ws = (char*)d_ws;  // ~75 MB
  __bf16* xb = (__bf16*)ws;     ws += (size_t)8192 * 1024 * 2;
  __bf16* WqkvT = (__bf16*)ws;  ws += (size_t)3072 * 1024 * 2;
  __bf16* WprojT = (__bf16*)ws; ws += (size_t)1024 * 1024 * 2;
  __bf16* Qs = (__bf16*)ws;     ws += (size_t)64 * 2048 * 64 * 2;
  __bf16* Ks = (__bf16*)ws;     ws += (size_t)64 * 2048 * 64 * 2;
  __bf16* VTs = (__bf16*)ws;    ws += (size_t)64 * 64 * 2048 * 2;
  __bf16* attn = xb;  // xb is dead after gemm_qkv; reuse its space

  static bool attrSet = false;
  if (!attrSet) {
    hipFuncSetAttribute((const void*)gemm_qkv,
                        hipFuncAttributeMaxDynamicSharedMemorySize, 65536);
    hipFuncSetAttribute((const void*)gemm_bt_f32out,
                        hipFuncAttributeMaxDynamicSharedMemorySize, 65536);
    attrSet = true;
  }

  f32_to_bf16<<<8192, 256, 0, stream>>>(x, xb);
  transpose_f32_bf16<<<dim3(96, 32), 256, 0, stream>>>(Wqkv, WqkvT, 1024, 3072);
  transpose_f32_bf16<<<dim3(32, 32), 256, 0, stream>>>(Wproj, WprojT, 1024, 1024);
  gemm_qkv<<<1536, 256, 65536, stream>>>(xb, WqkvT, Qs, Ks, VTs);
  flash_attn<<<dim3(64, 8), 256, 0, stream>>>(Qs, Ks, VTs, attn);
  gemm_bt_f32out<<<512, 256, 65536, stream>>>(attn, WprojT, out);
}